// Round 11
// baseline (75.800 us; speedup 1.0000x reference)
//
#include <hip/hip_runtime.h>
#include <cstdint>
#include <cstddef>

#define A_TOTAL 34125
#define BATCH 16
#define NBA (BATCH * A_TOTAL)
#define SBT 1024        // select block threads
#define PT2 25          // per-thread window elements = WIN/SBT
#define NB 1024         // histogram bins (1 px each)
#define CAND 768        // candidate buffer
#define NSEG (BATCH * 5)    // relabel segments (levels 0..4)
#define CCAP 16384      // claim-list capacity (data bound ~2.5k)
#define SELGRID 160
#define SCAN_GRID 1024
#define SCAN_THR 256

__device__ __constant__ int d_bounds[7] = {0, 25600, 32000, 33600, 34000, 34100, 34125};

#define MAXU 48     // max unique GT boxes per (batch, level)
#define MAXPOS 512  // max positives per level per batch
#define MAXC 32     // max candidates (max_num); data bound is 19
#define CLAIM_NONE 0x7FFFFFFF

// ---------------------------------------------------------------------------
// scan: 1024 blocks x 256 thr — ALL NBA-scale streaming at full-chip BW.
// claim init (int4), ctr init, conf BCE (part A), dense aligned float4 scan
// of bt: each chunk owns <=1 label slot (g%5==4), every anchor exactly once;
// writes posmap byte + inline part-B loss for positives. Per-block partials.
// ---------------------------------------------------------------------------
__global__ __launch_bounds__(SCAN_THR)
void scan_kernel(const float* __restrict__ bt,
                 const float* __restrict__ anchors,
                 const float* __restrict__ conf,
                 const float* __restrict__ loc,
                 int* __restrict__ claim,
                 uint8_t* __restrict__ posmap,
                 float* __restrict__ part,    // [SCAN_GRID][3]
                 int* __restrict__ ccnt,
                 float2* __restrict__ ctr) {
    const int tid = threadIdx.x;
    const int gtid = blockIdx.x * blockDim.x + tid;
    const int gsz = gridDim.x * blockDim.x;
    if (gtid == 0) *ccnt = 0;   // consumed only by later dispatches — safe

    int4* c4 = (int4*)claim;
    for (int i = gtid; i < NBA / 4; i += gsz)
        c4[i] = make_int4(CLAIM_NONE, CLAIM_NONE, CLAIM_NONE, CLAIM_NONE);
    for (int a = gtid; a < A_TOTAL; a += gsz) {
        const float4 ar = reinterpret_cast<const float4*>(anchors)[a];
        ctr[a] = make_float2((ar.x + ar.z) / 2.0f, (ar.y + ar.w) / 2.0f);
    }

    float bce = 0.0f, pos = 0.0f, l1 = 0.0f;

    // ---- part A: label-independent BCE term, streaming conf (float4)
    const float4* cf4 = (const float4*)conf;
    for (int i = gtid; i < NBA / 4; i += gsz) {
        const float4 z4 = cf4[i];
        const float zz[4] = {z4.x, z4.y, z4.z, z4.w};
        #pragma unroll
        for (int c = 0; c < 4; ++c) {
            const float z = zz[c];
            bce += fmaxf(z, 0.0f) + log1pf(expf(-fabsf(z)));
        }
    }

    // ---- bt label scan: chunk f4 holds the label of anchor (4*f4 + c)/5
    // when m = (4*f4)%5 != 0, c = 4-m. Every anchor covered exactly once.
    const float4* btv = (const float4*)bt;
    const int nchunk = NBA * 5 / 4;   // 682500, exact
    for (int f4 = gtid; f4 < nchunk; f4 += gsz) {
        const float4 v = btv[f4];
        const unsigned g0 = (unsigned)f4 * 4u;
        const unsigned m = g0 % 5u;
        if (m != 0u) {
            const unsigned c = 4u - m;
            const float val = (c == 0u) ? v.x : (c == 1u) ? v.y : (c == 2u) ? v.z : v.w;
            const unsigned i = (g0 + c) / 5u;
            const bool p = (val == 1.0f);
            posmap[i] = p ? 1 : 0;
            if (p) {
                // part B: original positive — bce correction, count, smooth-L1
                bce -= conf[i];
                pos += 1.0f;
                const float* tp = bt + (size_t)i * 5u;
                const float4 lv4 = reinterpret_cast<const float4*>(loc)[i];
                const float dv[4] = {lv4.x - tp[0], lv4.y - tp[1],
                                     lv4.z - tp[2], lv4.w - tp[3]};
                #pragma unroll
                for (int cc = 0; cc < 4; ++cc) {
                    const float ad = fabsf(dv[cc]);
                    l1 += (ad < 1.0f) ? 0.5f * dv[cc] * dv[cc] : ad - 0.5f;
                }
            }
        }
    }

    // ---- block reduce -> per-block partial (deterministic per slot)
    for (int off = 32; off > 0; off >>= 1) {
        bce += __shfl_down(bce, off);
        pos += __shfl_down(pos, off);
        l1  += __shfl_down(l1, off);
    }
    __shared__ float sb[3][4];
    const int wid = tid >> 6, lane = tid & 63;
    if (lane == 0) { sb[0][wid] = bce; sb[1][wid] = pos; sb[2][wid] = l1; }
    __syncthreads();
    if (tid == 0) {
        float B = 0, P = 0, L = 0;
        #pragma unroll
        for (int w = 0; w < 4; ++w) { B += sb[0][w]; P += sb[1][w]; L += sb[2][w]; }
        part[blockIdx.x * 3 + 0] = B;
        part[blockIdx.x * 3 + 1] = P;
        part[blockIdx.x * 3 + 2] = L;
    }
}

// ---------------------------------------------------------------------------
// dedup: 80 blocks x 256 thr (one per (b, level0..4)). Compact positives from
// posmap (order-independent dedup), decode+round, all-pairs count/rep,
// lexicographic rank -> sorted uniques + needy worklist.
// ---------------------------------------------------------------------------
__global__ __launch_bounds__(256)
void dedup_kernel(const float* __restrict__ bt,
                  const float* __restrict__ anchors,
                  const uint8_t* __restrict__ posmap,
                  float* __restrict__ uq,      // [NSEG][MAXU][4]
                  int* __restrict__ uc,        // [NSEG][MAXU]
                  int* __restrict__ nu_out,    // [NSEG]
                  int* __restrict__ mn_out,    // [NSEG]
                  int* __restrict__ wl,        // [NSEG][MAXU]
                  int* __restrict__ wlc)       // [NSEG]
{
    const int b = blockIdx.x / 5;
    const int lv = blockIdx.x % 5;
    const int seg = blockIdx.x;
    const unsigned bA = (unsigned)b * A_TOTAL;
    const int tid = threadIdx.x;

    __shared__ int s_pos[MAXPOS];
    __shared__ float t0[MAXPOS], t1[MAXPOS], t2[MAXPOS], t3[MAXPOS];
    __shared__ int s_cnt[MAXPOS];
    __shared__ uint8_t s_rep[MAXPOS];
    __shared__ int s_ucs[MAXU];
    __shared__ int s_np, s_nu;

    if (tid == 0) { s_np = 0; s_nu = 0; }
    __syncthreads();

    for (int a = d_bounds[lv] + tid; a < d_bounds[lv + 1]; a += blockDim.x) {
        if (posmap[bA + a]) {
            int p = atomicAdd(&s_np, 1);
            if (p < MAXPOS) s_pos[p] = a;
        }
    }
    __syncthreads();
    const int np_ = min(s_np, MAXPOS);

    // ---- decode + round (numpy op order, fp32)
    for (int p = tid; p < np_; p += blockDim.x) {
        int a = s_pos[p];
        const float* ar = anchors + (size_t)a * 4;
        float acx = (ar[0] + ar[2]) / 2.0f;
        float acy = (ar[1] + ar[3]) / 2.0f;
        float aw = ar[2] - ar[0];
        float ah = ar[3] - ar[1];
        const float* dd = bt + ((size_t)bA + a) * 5;
        float cx = acx + (dd[0] * 0.1f) * aw;
        float cy = acy + (dd[1] * 0.1f) * ah;
        float w = aw * expf(dd[2] * 0.2f);
        float h = ah * expf(dd[3] * 0.2f);
        t0[p] = rintf((cx - w / 2.0f) * 1000.0f) / 1000.0f;
        t1[p] = rintf((cy - h / 2.0f) * 1000.0f) / 1000.0f;
        t2[p] = rintf((cx + w / 2.0f) * 1000.0f) / 1000.0f;
        t3[p] = rintf((cy + h / 2.0f) * 1000.0f) / 1000.0f;
    }
    __syncthreads();

    // ---- all-pairs: count equals, find first occurrence (rep)
    for (int p = tid; p < np_; p += blockDim.x) {
        const float p0 = t0[p], p1 = t1[p], p2 = t2[p], p3 = t3[p];
        int cnt = 0, firstq = np_;
        for (int q = 0; q < np_; ++q) {
            bool eq = (t0[q] == p0) && (t1[q] == p1) && (t2[q] == p2) && (t3[q] == p3);
            if (eq) { cnt++; if (q < firstq) firstq = q; }
        }
        s_cnt[p] = cnt;
        bool rep = (firstq == p);
        s_rep[p] = rep ? 1 : 0;
        if (rep) atomicAdd(&s_nu, 1);
    }
    __syncthreads();

    // ---- reps compute lexicographic rank among reps -> sorted uniques
    float* uqp = uq + (size_t)seg * MAXU * 4;
    int* ucp = uc + (size_t)seg * MAXU;
    for (int p = tid; p < np_; p += blockDim.x) {
        if (!s_rep[p]) continue;
        const float p0 = t0[p], p1 = t1[p], p2 = t2[p], p3 = t3[p];
        int rank = 0;
        for (int q = 0; q < np_; ++q) {
            if (!s_rep[q]) continue;
            float q0 = t0[q], q1 = t1[q], q2 = t2[q], q3 = t3[q];
            bool lt = (q0 < p0) || (q0 == p0 && (q1 < p1 ||
                      (q1 == p1 && (q2 < p2 || (q2 == p2 && q3 < p3)))));
            if (lt) rank++;
        }
        if (rank < MAXU) {
            uqp[rank * 4 + 0] = p0; uqp[rank * 4 + 1] = p1;
            uqp[rank * 4 + 2] = p2; uqp[rank * 4 + 3] = p3;
            ucp[rank] = s_cnt[p];
            s_ucs[rank] = s_cnt[p];
        }
    }
    __syncthreads();

    if (tid == 0) {
        const int nu = min(s_nu, MAXU);
        nu_out[seg] = nu;
        int mn = 0;
        for (int j = 0; j < nu; ++j) mn = max(mn, s_ucs[j]);
        mn_out[seg] = mn;
        int n = 0;
        for (int ti = 0; ti < nu; ++ti)
            if (s_ucs[ti] != mn) wl[seg * MAXU + n++] = seg * MAXU + ti;
        wlc[seg] = n;
    }
}

// ---------------------------------------------------------------------------
// select: 160 blocks x 1024 thr grid-striding the needy worklist.
// Per entry: histogram -> boundary bin -> candidate collect -> exact rank
// sort -> parallel rank-pick -> atomicMin claim + append claim list.
// No cross-block reads within this kernel (claims resolved next dispatch).
// ---------------------------------------------------------------------------
__global__ __launch_bounds__(SBT)
void select_kernel(const float* __restrict__ conf,
                   const float2* __restrict__ ctr,
                   const float* __restrict__ uq,
                   const int* __restrict__ uc,
                   const int* __restrict__ nu_,
                   const int* __restrict__ mn_,
                   const int* __restrict__ wl,
                   const int* __restrict__ wlc,
                   int* __restrict__ claim,
                   int2* __restrict__ clist,
                   int* __restrict__ ccnt) {
    const int tid = threadIdx.x;

    __shared__ int s_hist[NB];
    __shared__ unsigned long long s_cand[CAND];
    __shared__ unsigned long long s_srt[MAXC];
    __shared__ float s_sc[MAXC];
    __shared__ int s_c, s_B;

    for (int w = blockIdx.x; ; w += gridDim.x) {
        // locate worklist entry w via prefix over 80 segment counts
        int cum = 0, ent = -1;
        for (int i = 0; i < NSEG; ++i) {
            int c = wlc[i];
            if (ent < 0 && w < cum + c) ent = wl[i * MAXU + (w - cum)];
            cum += c;
        }
        if (w >= cum) return;

        const int ti = ent % MAXU;
        const int sg = ent / MAXU;
        const int li = sg % 5;
        const int b  = sg / 5;

        int nus[5];
        #pragma unroll
        for (int l = 0; l < 5; ++l) nus[l] = nu_[b * 5 + l];

        // window-advance quirk: only non-empty levels (l<=li) advance
        int s = -25600;
        float tmpw = 160.0f;
        for (int l = 0; l <= li; ++l) {
            if (nus[l] != 0) { s += (int)(tmpw * tmpw); tmpw *= 0.5f; }
        }

        const int mn = mn_[sg];
        const int cnt = uc[(size_t)sg * MAXU + ti];
        const int need = mn - cnt;
        const int K = min(mn, MAXC);
        const unsigned bA = (unsigned)b * A_TOTAL;

        const float* g = uq + ((size_t)sg * MAXU + ti) * 4;
        const float gcx = (g[0] + g[2]) / 2.0f;
        const float gcy = (g[1] + g[3]) / 2.0f;

        float cxr[PT2], cyr[PT2];
        #pragma unroll
        for (int i = 0; i < PT2; ++i) {
            const float2 c = ctr[s + tid + (i << 10)];
            cxr[i] = c.x;
            cyr[i] = c.y;
        }

        s_hist[tid] = 0;
        if (tid == 0) s_c = 0;
        __syncthreads();

        #pragma unroll
        for (int i = 0; i < PT2; ++i) {
            float d = hypotf(cxr[i] - gcx, cyr[i] - gcy);
            int bin = min(NB - 1, (int)d);
            atomicAdd(&s_hist[bin], 1);
        }
        __syncthreads();

        // one wave: boundary bin B* (smallest bin with cum >= K)
        if (tid < 64) {
            const int base = tid << 4;
            int part[16], psum = 0;
            #pragma unroll
            for (int i = 0; i < 16; ++i) { part[i] = s_hist[base + i]; psum += part[i]; }
            int run = psum;
            #pragma unroll
            for (int off = 1; off < 64; off <<= 1) {
                int o = __shfl_up(run, off);
                if (tid >= off) run += o;
            }
            const int excl = run - psum;
            if (excl < K && excl + psum >= K) {
                int c = excl, bs = base + 15;
                for (int i = 0; i < 16; ++i) { c += part[i]; if (c >= K) { bs = base + i; break; } }
                s_B = bs;
            }
        }
        __syncthreads();
        const int B = s_B;

        // collect candidates (bin <= B*), exact 64-bit keys (dist, window idx)
        #pragma unroll
        for (int i = 0; i < PT2; ++i) {
            float d = hypotf(cxr[i] - gcx, cyr[i] - gcy);
            int bin = min(NB - 1, (int)d);
            if (bin <= B) {
                int p = atomicAdd(&s_c, 1);
                if (p < CAND)
                    s_cand[p] = (((unsigned long long)__float_as_uint(d)) << 32) |
                                (unsigned)(tid + (i << 10));
            }
        }
        __syncthreads();
        const int C = min(s_c, CAND);

        // parallel rank sort: stable argsort by (dist, window idx); keep top K
        if (tid < C) {
            const unsigned long long mykey = s_cand[tid];
            int rank = 0;
            for (int j = 0; j < C; ++j) rank += (s_cand[j] < mykey) ? 1 : 0;
            if (rank < K) s_srt[rank] = mykey;
        }
        __syncthreads();

        if (tid < K) {
            const int o = (int)(s_srt[tid] & 0xffffffffULL);
            const float z = conf[bA + s + o];
            s_sc[tid] = 1.0f / (1.0f + expf(-z));
        }
        __syncthreads();

        // parallel rank-pick: top `need` by (score desc, cand idx desc);
        // within-unique rel order irrelevant -> claim priority = (li,ti)
        if (tid < K) {
            const float my = s_sc[tid];
            int r = 0;
            for (int j = 0; j < K; ++j) {
                const float oj = s_sc[j];
                r += (oj > my || (oj == my && j > tid)) ? 1 : 0;
            }
            if (r < need) {
                const int o = (int)(s_srt[tid] & 0xffffffffULL);
                const int idx = (int)(bA + s + o);
                const int seq = li * MAXU + ti;
                atomicMin(&claim[idx], seq);
                int p = atomicAdd(ccnt, 1);
                if (p < CCAP) clist[p] = make_int2(idx, seq);
            }
        }
        __syncthreads();
    }
}

// ---------------------------------------------------------------------------
// finalize: 1 block x 1024 thr. Part C over the compact claim list (winner
// check + !orig-pos filter, inline encode); each thread also adds its scan
// partial slot; fixed-tree block reduce; write the 3 outputs.
// ---------------------------------------------------------------------------
__global__ __launch_bounds__(1024)
void finalize_kernel(const float* __restrict__ conf,
                     const float* __restrict__ loc,
                     const float* __restrict__ bt,
                     const float* __restrict__ anchors,
                     const float* __restrict__ uq,
                     const int2* __restrict__ clist,
                     const int* __restrict__ ccnt,
                     const int* __restrict__ claim,
                     const float* __restrict__ part,
                     float* __restrict__ out) {
    const int tid = threadIdx.x;
    float bce = 0.0f, pos = 0.0f, l1 = 0.0f;
    const int cn = min(*ccnt, CCAP);
    for (int e = tid; e < cn; e += blockDim.x) {
        const int2 ent = clist[e];
        const int idx = ent.x;
        if (claim[idx] != ent.y) continue;                 // lost arbitration
        if (bt[(size_t)idx * 5 + 4] == 1.0f) continue;     // labels != 1 filter
        bce -= conf[idx];
        pos += 1.0f;
        const int uli = ent.y / MAXU;
        const int uti = ent.y - uli * MAXU;
        const int b = idx / A_TOTAL;
        const int a = idx - b * A_TOTAL;
        const float* g = uq + ((size_t)(b * 5 + uli) * MAXU + uti) * 4;
        const float g0 = g[0], g1 = g[1], g2 = g[2], g3 = g[3];
        const float gcx = (g0 + g2) / 2.0f, gcy = (g1 + g3) / 2.0f;
        const float gw = g2 - g0, gh = g3 - g1;
        const float* ar = anchors + (size_t)a * 4;
        const float acx = (ar[0] + ar[2]) / 2.0f;
        const float acy = (ar[1] + ar[3]) / 2.0f;
        const float aw = ar[2] - ar[0];
        const float ah = ar[3] - ar[1];
        float ep[4];
        ep[0] = (gcx - acx) / (aw * 0.1f);
        ep[1] = (gcy - acy) / (ah * 0.1f);
        ep[2] = logf(fmaxf(gw, 1e-6f) / aw) / 0.2f;
        ep[3] = logf(fmaxf(gh, 1e-6f) / ah) / 0.2f;
        const float4 lvv = reinterpret_cast<const float4*>(loc)[idx];
        const float lvf[4] = {lvv.x, lvv.y, lvv.z, lvv.w};
        #pragma unroll
        for (int c = 0; c < 4; ++c) {
            const float dd = lvf[c] - ep[c];
            const float ad = fabsf(dd);
            l1 += (ad < 1.0f) ? 0.5f * dd * dd : ad - 0.5f;
        }
    }

    // each thread adds its scan partial slot (SCAN_GRID == blockDim.x)
    if (tid < SCAN_GRID) {
        bce += part[tid * 3 + 0];
        pos += part[tid * 3 + 1];
        l1  += part[tid * 3 + 2];
    }

    for (int off = 32; off > 0; off >>= 1) {
        bce += __shfl_down(bce, off);
        pos += __shfl_down(pos, off);
        l1  += __shfl_down(l1, off);
    }
    __shared__ float sb[3][16];
    const int wid = tid >> 6, lane = tid & 63;
    if (lane == 0) { sb[0][wid] = bce; sb[1][wid] = pos; sb[2][wid] = l1; }
    __syncthreads();
    if (tid == 0) {
        float B = 0, P = 0, L = 0;
        #pragma unroll
        for (int w = 0; w < 16; ++w) { B += sb[0][w]; P += sb[1][w]; L += sb[2][w]; }
        const double a0 = (double)B;
        const double a1 = (double)P;
        const double a2 = (double)L;
        const double np_ = a1 > 1.0 ? a1 : 1.0;
        const double cls = a0 / np_;          // CLS_W = 1.0
        const double lcl = 2.0 * a2 / np_;    // LOC_W = 2.0
        out[0] = (float)cls;
        out[1] = (float)lcl;
        out[2] = (float)(cls + lcl);
    }
}

// ---------------------------------------------------------------------------
extern "C" void kernel_launch(void* const* d_in, const int* in_sizes, int n_in,
                              void* d_out, int out_size, void* d_ws, size_t ws_size,
                              hipStream_t stream) {
    const float* conf    = (const float*)d_in[0];
    const float* loc     = (const float*)d_in[1];
    const float* bt      = (const float*)d_in[2];
    const float* anchors = (const float*)d_in[3];
    float* out = (float*)d_out;

    char* ws = (char*)d_ws;
    size_t off = 0;
    int* ccnt       = (int*)(ws + off);    off += 64;
    float* part     = (float*)(ws + off);  off += (size_t)SCAN_GRID * 3 * sizeof(float);
    int* claim      = (int*)(ws + off);    off += (size_t)NBA * sizeof(int);
    uint8_t* posmap = (uint8_t*)(ws + off); off += ((size_t)NBA + 63) & ~63ull;
    float* uq       = (float*)(ws + off);  off += (size_t)NSEG * MAXU * 4 * sizeof(float);
    int* uc         = (int*)(ws + off);    off += (size_t)NSEG * MAXU * sizeof(int);
    int* nu_        = (int*)(ws + off);    off += (size_t)NSEG * sizeof(int);
    int* mn_        = (int*)(ws + off);    off += (size_t)NSEG * sizeof(int);
    int* wl         = (int*)(ws + off);    off += (size_t)NSEG * MAXU * sizeof(int);
    int* wlc        = (int*)(ws + off);    off += ((size_t)NSEG * sizeof(int) + 15) & ~15ull;
    int2* clist     = (int2*)(ws + off);   off += (size_t)CCAP * sizeof(int2);
    float2* ctr     = (float2*)(ws + off); off += (size_t)A_TOTAL * sizeof(float2);

    scan_kernel<<<SCAN_GRID, SCAN_THR, 0, stream>>>(bt, anchors, conf, loc, claim,
                                                    posmap, part, ccnt, ctr);
    dedup_kernel<<<NSEG, 256, 0, stream>>>(bt, anchors, posmap, uq, uc, nu_, mn_,
                                           wl, wlc);
    select_kernel<<<SELGRID, SBT, 0, stream>>>(conf, ctr, uq, uc, nu_, mn_, wl, wlc,
                                               claim, clist, ccnt);
    finalize_kernel<<<1, 1024, 0, stream>>>(conf, loc, bt, anchors, uq, clist, ccnt,
                                            claim, part, out);
}

// Round 12
// 56.188 us; speedup vs baseline: 1.3491x; 1.3491x over previous
//
#include <hip/hip_runtime.h>
#include <cstdint>
#include <cstddef>

#define A_TOTAL 34125
#define BATCH 16
#define NBA (BATCH * A_TOTAL)
#define SBT 1024        // select block threads
#define PT2 25          // per-thread window elements = WIN/SBT
#define NB 1024         // histogram bins (1 px each)
#define CAND 768        // candidate buffer
#define NSEG (BATCH * 5)    // relabel segments (levels 0..4)
#define CCAP 16384      // claim-list capacity (data bound ~2.5k)
#define SELGRID 160
#define SCAN_GRID 1024
#define SCAN_THR 256

__device__ __constant__ int d_bounds[7] = {0, 25600, 32000, 33600, 34000, 34100, 34125};

#define MAXU 48     // max unique GT boxes per (batch, level)
#define MAXPOS 512  // max positives per level per batch
#define MAXC 32     // max candidates (max_num); data bound is 19
#define CLAIM_NONE 0x7FFFFFFF

// ---------------------------------------------------------------------------
// scan: 1024 blocks x 256 thr — ALL NBA-scale streaming at full-chip BW.
// claim init (int4), ctr init, conf BCE (part A), dense aligned float4 scan
// of bt: each chunk owns <=1 label slot (g%5==4), every anchor exactly once;
// writes posmap byte + inline part-B loss for positives. Per-block partials.
// ---------------------------------------------------------------------------
__global__ __launch_bounds__(SCAN_THR)
void scan_kernel(const float* __restrict__ bt,
                 const float* __restrict__ anchors,
                 const float* __restrict__ conf,
                 const float* __restrict__ loc,
                 int* __restrict__ claim,
                 uint8_t* __restrict__ posmap,
                 float* __restrict__ part,    // [SCAN_GRID][3]
                 int* __restrict__ ccnt,
                 float2* __restrict__ ctr) {
    const int tid = threadIdx.x;
    const int gtid = blockIdx.x * blockDim.x + tid;
    const int gsz = gridDim.x * blockDim.x;
    if (gtid == 0) *ccnt = 0;   // consumed only by later dispatches — safe

    int4* c4 = (int4*)claim;
    for (int i = gtid; i < NBA / 4; i += gsz)
        c4[i] = make_int4(CLAIM_NONE, CLAIM_NONE, CLAIM_NONE, CLAIM_NONE);
    for (int a = gtid; a < A_TOTAL; a += gsz) {
        const float4 ar = reinterpret_cast<const float4*>(anchors)[a];
        ctr[a] = make_float2((ar.x + ar.z) / 2.0f, (ar.y + ar.w) / 2.0f);
    }

    float bce = 0.0f, pos = 0.0f, l1 = 0.0f;

    // ---- part A: label-independent BCE term, streaming conf (float4)
    const float4* cf4 = (const float4*)conf;
    for (int i = gtid; i < NBA / 4; i += gsz) {
        const float4 z4 = cf4[i];
        const float zz[4] = {z4.x, z4.y, z4.z, z4.w};
        #pragma unroll
        for (int c = 0; c < 4; ++c) {
            const float z = zz[c];
            bce += fmaxf(z, 0.0f) + log1pf(expf(-fabsf(z)));
        }
    }

    // ---- bt label scan: chunk f4 holds the label of anchor (4*f4 + c)/5
    // when m = (4*f4)%5 != 0, c = 4-m. Every anchor covered exactly once.
    const float4* btv = (const float4*)bt;
    const int nchunk = NBA * 5 / 4;   // 682500, exact
    for (int f4 = gtid; f4 < nchunk; f4 += gsz) {
        const float4 v = btv[f4];
        const unsigned g0 = (unsigned)f4 * 4u;
        const unsigned m = g0 % 5u;
        if (m != 0u) {
            const unsigned c = 4u - m;
            const float val = (c == 0u) ? v.x : (c == 1u) ? v.y : (c == 2u) ? v.z : v.w;
            const unsigned i = (g0 + c) / 5u;
            const bool p = (val == 1.0f);
            posmap[i] = p ? 1 : 0;
            if (p) {
                // part B: original positive — bce correction, count, smooth-L1
                bce -= conf[i];
                pos += 1.0f;
                const float* tp = bt + (size_t)i * 5u;
                const float4 lv4 = reinterpret_cast<const float4*>(loc)[i];
                const float dv[4] = {lv4.x - tp[0], lv4.y - tp[1],
                                     lv4.z - tp[2], lv4.w - tp[3]};
                #pragma unroll
                for (int cc = 0; cc < 4; ++cc) {
                    const float ad = fabsf(dv[cc]);
                    l1 += (ad < 1.0f) ? 0.5f * dv[cc] * dv[cc] : ad - 0.5f;
                }
            }
        }
    }

    // ---- block reduce -> per-block partial (deterministic per slot)
    for (int off = 32; off > 0; off >>= 1) {
        bce += __shfl_down(bce, off);
        pos += __shfl_down(pos, off);
        l1  += __shfl_down(l1, off);
    }
    __shared__ float sb[3][4];
    const int wid = tid >> 6, lane = tid & 63;
    if (lane == 0) { sb[0][wid] = bce; sb[1][wid] = pos; sb[2][wid] = l1; }
    __syncthreads();
    if (tid == 0) {
        float B = 0, P = 0, L = 0;
        #pragma unroll
        for (int w = 0; w < 4; ++w) { B += sb[0][w]; P += sb[1][w]; L += sb[2][w]; }
        part[blockIdx.x * 3 + 0] = B;
        part[blockIdx.x * 3 + 1] = P;
        part[blockIdx.x * 3 + 2] = L;
    }
}

// ---------------------------------------------------------------------------
// dedup: 80 blocks x 256 thr (one per (b, level0..4)). Vectorized uint4
// posmap scan (16B/thread/iter — avoids per-iteration latency serialization),
// decode+round, all-pairs count/rep, lexicographic rank -> sorted uniques +
// needy worklist. Dedup outputs are order-independent of collection order.
// ---------------------------------------------------------------------------
__global__ __launch_bounds__(256)
void dedup_kernel(const float* __restrict__ bt,
                  const float* __restrict__ anchors,
                  const uint8_t* __restrict__ posmap,
                  float* __restrict__ uq,      // [NSEG][MAXU][4]
                  int* __restrict__ uc,        // [NSEG][MAXU]
                  int* __restrict__ nu_out,    // [NSEG]
                  int* __restrict__ mn_out,    // [NSEG]
                  int* __restrict__ wl,        // [NSEG][MAXU]
                  int* __restrict__ wlc)       // [NSEG]
{
    const int b = blockIdx.x / 5;
    const int lv = blockIdx.x % 5;
    const int seg = blockIdx.x;
    const unsigned bA = (unsigned)b * A_TOTAL;
    const int tid = threadIdx.x;

    __shared__ int s_pos[MAXPOS];
    __shared__ float t0[MAXPOS], t1[MAXPOS], t2[MAXPOS], t3[MAXPOS];
    __shared__ int s_cnt[MAXPOS];
    __shared__ uint8_t s_rep[MAXPOS];
    __shared__ int s_ucs[MAXU];
    __shared__ int s_np, s_nu;

    if (tid == 0) { s_np = 0; s_nu = 0; }
    __syncthreads();

    // ---- vectorized positive collection from posmap byte range [gs, ge)
    {
        const unsigned gs = bA + (unsigned)d_bounds[lv];
        const unsigned ge = bA + (unsigned)d_bounds[lv + 1];
        const unsigned astart = (gs + 15u) & ~15u;
        const unsigned aend_raw = ge & ~15u;
        const unsigned hend = min(astart, ge);
        for (unsigned g = gs + tid; g < hend; g += blockDim.x)
            if (posmap[g]) {
                int p = atomicAdd(&s_np, 1);
                if (p < MAXPOS) s_pos[p] = (int)(g - bA);
            }
        if (aend_raw > astart) {
            const uint4* pm4 = (const uint4*)(posmap + astart);
            const unsigned n16 = (aend_raw - astart) >> 4;
            for (unsigned c = tid; c < n16; c += blockDim.x) {
                const uint4 v = pm4[c];
                if (v.x | v.y | v.z | v.w) {
                    const unsigned base = astart + (c << 4);
                    const unsigned wv[4] = {v.x, v.y, v.z, v.w};
                    #pragma unroll
                    for (int w = 0; w < 4; ++w) {
                        #pragma unroll
                        for (int byi = 0; byi < 4; ++byi) {
                            if ((wv[w] >> (8 * byi)) & 0xffu) {
                                int p = atomicAdd(&s_np, 1);
                                if (p < MAXPOS)
                                    s_pos[p] = (int)(base + 4u * w + byi - bA);
                            }
                        }
                    }
                }
            }
            for (unsigned g = aend_raw + tid; g < ge; g += blockDim.x)
                if (posmap[g]) {
                    int p = atomicAdd(&s_np, 1);
                    if (p < MAXPOS) s_pos[p] = (int)(g - bA);
                }
        }
    }
    __syncthreads();
    const int np_ = min(s_np, MAXPOS);

    // ---- decode + round (numpy op order, fp32)
    for (int p = tid; p < np_; p += blockDim.x) {
        int a = s_pos[p];
        const float* ar = anchors + (size_t)a * 4;
        float acx = (ar[0] + ar[2]) / 2.0f;
        float acy = (ar[1] + ar[3]) / 2.0f;
        float aw = ar[2] - ar[0];
        float ah = ar[3] - ar[1];
        const float* dd = bt + ((size_t)bA + a) * 5;
        float cx = acx + (dd[0] * 0.1f) * aw;
        float cy = acy + (dd[1] * 0.1f) * ah;
        float w = aw * expf(dd[2] * 0.2f);
        float h = ah * expf(dd[3] * 0.2f);
        t0[p] = rintf((cx - w / 2.0f) * 1000.0f) / 1000.0f;
        t1[p] = rintf((cy - h / 2.0f) * 1000.0f) / 1000.0f;
        t2[p] = rintf((cx + w / 2.0f) * 1000.0f) / 1000.0f;
        t3[p] = rintf((cy + h / 2.0f) * 1000.0f) / 1000.0f;
    }
    __syncthreads();

    // ---- all-pairs: count equals, find first occurrence (rep)
    for (int p = tid; p < np_; p += blockDim.x) {
        const float p0 = t0[p], p1 = t1[p], p2 = t2[p], p3 = t3[p];
        int cnt = 0, firstq = np_;
        for (int q = 0; q < np_; ++q) {
            bool eq = (t0[q] == p0) && (t1[q] == p1) && (t2[q] == p2) && (t3[q] == p3);
            if (eq) { cnt++; if (q < firstq) firstq = q; }
        }
        s_cnt[p] = cnt;
        bool rep = (firstq == p);
        s_rep[p] = rep ? 1 : 0;
        if (rep) atomicAdd(&s_nu, 1);
    }
    __syncthreads();

    // ---- reps compute lexicographic rank among reps -> sorted uniques
    float* uqp = uq + (size_t)seg * MAXU * 4;
    int* ucp = uc + (size_t)seg * MAXU;
    for (int p = tid; p < np_; p += blockDim.x) {
        if (!s_rep[p]) continue;
        const float p0 = t0[p], p1 = t1[p], p2 = t2[p], p3 = t3[p];
        int rank = 0;
        for (int q = 0; q < np_; ++q) {
            if (!s_rep[q]) continue;
            float q0 = t0[q], q1 = t1[q], q2 = t2[q], q3 = t3[q];
            bool lt = (q0 < p0) || (q0 == p0 && (q1 < p1 ||
                      (q1 == p1 && (q2 < p2 || (q2 == p2 && q3 < p3)))));
            if (lt) rank++;
        }
        if (rank < MAXU) {
            uqp[rank * 4 + 0] = p0; uqp[rank * 4 + 1] = p1;
            uqp[rank * 4 + 2] = p2; uqp[rank * 4 + 3] = p3;
            ucp[rank] = s_cnt[p];
            s_ucs[rank] = s_cnt[p];
        }
    }
    __syncthreads();

    if (tid == 0) {
        const int nu = min(s_nu, MAXU);
        nu_out[seg] = nu;
        int mn = 0;
        for (int j = 0; j < nu; ++j) mn = max(mn, s_ucs[j]);
        mn_out[seg] = mn;
        int n = 0;
        for (int ti = 0; ti < nu; ++ti)
            if (s_ucs[ti] != mn) wl[seg * MAXU + n++] = seg * MAXU + ti;
        wlc[seg] = n;
    }
}

// ---------------------------------------------------------------------------
// select: 160 blocks x 1024 thr grid-striding the needy worklist.
// Per entry: histogram -> boundary bin -> candidate collect -> exact rank
// sort -> parallel rank-pick -> atomicMin claim + append claim list.
// No cross-block reads within this kernel (claims resolved next dispatch).
// ---------------------------------------------------------------------------
__global__ __launch_bounds__(SBT)
void select_kernel(const float* __restrict__ conf,
                   const float2* __restrict__ ctr,
                   const float* __restrict__ uq,
                   const int* __restrict__ uc,
                   const int* __restrict__ nu_,
                   const int* __restrict__ mn_,
                   const int* __restrict__ wl,
                   const int* __restrict__ wlc,
                   int* __restrict__ claim,
                   int2* __restrict__ clist,
                   int* __restrict__ ccnt) {
    const int tid = threadIdx.x;

    __shared__ int s_hist[NB];
    __shared__ unsigned long long s_cand[CAND];
    __shared__ unsigned long long s_srt[MAXC];
    __shared__ float s_sc[MAXC];
    __shared__ int s_c, s_B;

    for (int w = blockIdx.x; ; w += gridDim.x) {
        // locate worklist entry w via prefix over 80 segment counts
        int cum = 0, ent = -1;
        for (int i = 0; i < NSEG; ++i) {
            int c = wlc[i];
            if (ent < 0 && w < cum + c) ent = wl[i * MAXU + (w - cum)];
            cum += c;
        }
        if (w >= cum) return;

        const int ti = ent % MAXU;
        const int sg = ent / MAXU;
        const int li = sg % 5;
        const int b  = sg / 5;

        int nus[5];
        #pragma unroll
        for (int l = 0; l < 5; ++l) nus[l] = nu_[b * 5 + l];

        // window-advance quirk: only non-empty levels (l<=li) advance
        int s = -25600;
        float tmpw = 160.0f;
        for (int l = 0; l <= li; ++l) {
            if (nus[l] != 0) { s += (int)(tmpw * tmpw); tmpw *= 0.5f; }
        }

        const int mn = mn_[sg];
        const int cnt = uc[(size_t)sg * MAXU + ti];
        const int need = mn - cnt;
        const int K = min(mn, MAXC);
        const unsigned bA = (unsigned)b * A_TOTAL;

        const float* g = uq + ((size_t)sg * MAXU + ti) * 4;
        const float gcx = (g[0] + g[2]) / 2.0f;
        const float gcy = (g[1] + g[3]) / 2.0f;

        float cxr[PT2], cyr[PT2];
        #pragma unroll
        for (int i = 0; i < PT2; ++i) {
            const float2 c = ctr[s + tid + (i << 10)];
            cxr[i] = c.x;
            cyr[i] = c.y;
        }

        s_hist[tid] = 0;
        if (tid == 0) s_c = 0;
        __syncthreads();

        #pragma unroll
        for (int i = 0; i < PT2; ++i) {
            float d = hypotf(cxr[i] - gcx, cyr[i] - gcy);
            int bin = min(NB - 1, (int)d);
            atomicAdd(&s_hist[bin], 1);
        }
        __syncthreads();

        // one wave: boundary bin B* (smallest bin with cum >= K)
        if (tid < 64) {
            const int base = tid << 4;
            int part[16], psum = 0;
            #pragma unroll
            for (int i = 0; i < 16; ++i) { part[i] = s_hist[base + i]; psum += part[i]; }
            int run = psum;
            #pragma unroll
            for (int off = 1; off < 64; off <<= 1) {
                int o = __shfl_up(run, off);
                if (tid >= off) run += o;
            }
            const int excl = run - psum;
            if (excl < K && excl + psum >= K) {
                int c = excl, bs = base + 15;
                for (int i = 0; i < 16; ++i) { c += part[i]; if (c >= K) { bs = base + i; break; } }
                s_B = bs;
            }
        }
        __syncthreads();
        const int B = s_B;

        // collect candidates (bin <= B*), exact 64-bit keys (dist, window idx)
        #pragma unroll
        for (int i = 0; i < PT2; ++i) {
            float d = hypotf(cxr[i] - gcx, cyr[i] - gcy);
            int bin = min(NB - 1, (int)d);
            if (bin <= B) {
                int p = atomicAdd(&s_c, 1);
                if (p < CAND)
                    s_cand[p] = (((unsigned long long)__float_as_uint(d)) << 32) |
                                (unsigned)(tid + (i << 10));
            }
        }
        __syncthreads();
        const int C = min(s_c, CAND);

        // parallel rank sort: stable argsort by (dist, window idx); keep top K
        if (tid < C) {
            const unsigned long long mykey = s_cand[tid];
            int rank = 0;
            for (int j = 0; j < C; ++j) rank += (s_cand[j] < mykey) ? 1 : 0;
            if (rank < K) s_srt[rank] = mykey;
        }
        __syncthreads();

        if (tid < K) {
            const int o = (int)(s_srt[tid] & 0xffffffffULL);
            const float z = conf[bA + s + o];
            s_sc[tid] = 1.0f / (1.0f + expf(-z));
        }
        __syncthreads();

        // parallel rank-pick: top `need` by (score desc, cand idx desc);
        // within-unique rel order irrelevant -> claim priority = (li,ti)
        if (tid < K) {
            const float my = s_sc[tid];
            int r = 0;
            for (int j = 0; j < K; ++j) {
                const float oj = s_sc[j];
                r += (oj > my || (oj == my && j > tid)) ? 1 : 0;
            }
            if (r < need) {
                const int o = (int)(s_srt[tid] & 0xffffffffULL);
                const int idx = (int)(bA + s + o);
                const int seq = li * MAXU + ti;
                atomicMin(&claim[idx], seq);
                int p = atomicAdd(ccnt, 1);
                if (p < CCAP) clist[p] = make_int2(idx, seq);
            }
        }
        __syncthreads();
    }
}

// ---------------------------------------------------------------------------
// finalize: 1 block x 1024 thr. Part C over the compact claim list (winner
// check + !orig-pos filter, inline encode); each thread also adds its scan
// partial slot; fixed-tree block reduce; write the 3 outputs.
// ---------------------------------------------------------------------------
__global__ __launch_bounds__(1024)
void finalize_kernel(const float* __restrict__ conf,
                     const float* __restrict__ loc,
                     const float* __restrict__ bt,
                     const float* __restrict__ anchors,
                     const float* __restrict__ uq,
                     const int2* __restrict__ clist,
                     const int* __restrict__ ccnt,
                     const int* __restrict__ claim,
                     const float* __restrict__ part,
                     float* __restrict__ out) {
    const int tid = threadIdx.x;
    float bce = 0.0f, pos = 0.0f, l1 = 0.0f;
    const int cn = min(*ccnt, CCAP);
    for (int e = tid; e < cn; e += blockDim.x) {
        const int2 ent = clist[e];
        const int idx = ent.x;
        if (claim[idx] != ent.y) continue;                 // lost arbitration
        if (bt[(size_t)idx * 5 + 4] == 1.0f) continue;     // labels != 1 filter
        bce -= conf[idx];
        pos += 1.0f;
        const int uli = ent.y / MAXU;
        const int uti = ent.y - uli * MAXU;
        const int b = idx / A_TOTAL;
        const int a = idx - b * A_TOTAL;
        const float* g = uq + ((size_t)(b * 5 + uli) * MAXU + uti) * 4;
        const float g0 = g[0], g1 = g[1], g2 = g[2], g3 = g[3];
        const float gcx = (g0 + g2) / 2.0f, gcy = (g1 + g3) / 2.0f;
        const float gw = g2 - g0, gh = g3 - g1;
        const float* ar = anchors + (size_t)a * 4;
        const float acx = (ar[0] + ar[2]) / 2.0f;
        const float acy = (ar[1] + ar[3]) / 2.0f;
        const float aw = ar[2] - ar[0];
        const float ah = ar[3] - ar[1];
        float ep[4];
        ep[0] = (gcx - acx) / (aw * 0.1f);
        ep[1] = (gcy - acy) / (ah * 0.1f);
        ep[2] = logf(fmaxf(gw, 1e-6f) / aw) / 0.2f;
        ep[3] = logf(fmaxf(gh, 1e-6f) / ah) / 0.2f;
        const float4 lvv = reinterpret_cast<const float4*>(loc)[idx];
        const float lvf[4] = {lvv.x, lvv.y, lvv.z, lvv.w};
        #pragma unroll
        for (int c = 0; c < 4; ++c) {
            const float dd = lvf[c] - ep[c];
            const float ad = fabsf(dd);
            l1 += (ad < 1.0f) ? 0.5f * dd * dd : ad - 0.5f;
        }
    }

    // each thread adds its scan partial slot (SCAN_GRID == blockDim.x)
    if (tid < SCAN_GRID) {
        bce += part[tid * 3 + 0];
        pos += part[tid * 3 + 1];
        l1  += part[tid * 3 + 2];
    }

    for (int off = 32; off > 0; off >>= 1) {
        bce += __shfl_down(bce, off);
        pos += __shfl_down(pos, off);
        l1  += __shfl_down(l1, off);
    }
    __shared__ float sb[3][16];
    const int wid = tid >> 6, lane = tid & 63;
    if (lane == 0) { sb[0][wid] = bce; sb[1][wid] = pos; sb[2][wid] = l1; }
    __syncthreads();
    if (tid == 0) {
        float B = 0, P = 0, L = 0;
        #pragma unroll
        for (int w = 0; w < 16; ++w) { B += sb[0][w]; P += sb[1][w]; L += sb[2][w]; }
        const double a0 = (double)B;
        const double a1 = (double)P;
        const double a2 = (double)L;
        const double np_ = a1 > 1.0 ? a1 : 1.0;
        const double cls = a0 / np_;          // CLS_W = 1.0
        const double lcl = 2.0 * a2 / np_;    // LOC_W = 2.0
        out[0] = (float)cls;
        out[1] = (float)lcl;
        out[2] = (float)(cls + lcl);
    }
}

// ---------------------------------------------------------------------------
extern "C" void kernel_launch(void* const* d_in, const int* in_sizes, int n_in,
                              void* d_out, int out_size, void* d_ws, size_t ws_size,
                              hipStream_t stream) {
    const float* conf    = (const float*)d_in[0];
    const float* loc     = (const float*)d_in[1];
    const float* bt      = (const float*)d_in[2];
    const float* anchors = (const float*)d_in[3];
    float* out = (float*)d_out;

    char* ws = (char*)d_ws;
    size_t off = 0;
    int* ccnt       = (int*)(ws + off);    off += 64;
    float* part     = (float*)(ws + off);  off += (size_t)SCAN_GRID * 3 * sizeof(float);
    int* claim      = (int*)(ws + off);    off += (size_t)NBA * sizeof(int);
    uint8_t* posmap = (uint8_t*)(ws + off); off += ((size_t)NBA + 63) & ~63ull;
    float* uq       = (float*)(ws + off);  off += (size_t)NSEG * MAXU * 4 * sizeof(float);
    int* uc         = (int*)(ws + off);    off += (size_t)NSEG * MAXU * sizeof(int);
    int* nu_        = (int*)(ws + off);    off += (size_t)NSEG * sizeof(int);
    int* mn_        = (int*)(ws + off);    off += (size_t)NSEG * sizeof(int);
    int* wl         = (int*)(ws + off);    off += (size_t)NSEG * MAXU * sizeof(int);
    int* wlc        = (int*)(ws + off);    off += ((size_t)NSEG * sizeof(int) + 15) & ~15ull;
    int2* clist     = (int2*)(ws + off);   off += (size_t)CCAP * sizeof(int2);
    float2* ctr     = (float2*)(ws + off); off += (size_t)A_TOTAL * sizeof(float2);

    scan_kernel<<<SCAN_GRID, SCAN_THR, 0, stream>>>(bt, anchors, conf, loc, claim,
                                                    posmap, part, ccnt, ctr);
    dedup_kernel<<<NSEG, 256, 0, stream>>>(bt, anchors, posmap, uq, uc, nu_, mn_,
                                           wl, wlc);
    select_kernel<<<SELGRID, SBT, 0, stream>>>(conf, ctr, uq, uc, nu_, mn_, wl, wlc,
                                               claim, clist, ccnt);
    finalize_kernel<<<1, 1024, 0, stream>>>(conf, loc, bt, anchors, uq, clist, ccnt,
                                            claim, part, out);
}